// Round 1
// baseline (408.582 us; speedup 1.0000x reference)
//
#include <hip/hip_runtime.h>

#define B_SZ 8
#define N_SZ 4096
#define M_SZ 2048
#define D_SZ 512

typedef __attribute__((ext_vector_type(8))) short bf16x8;
typedef __attribute__((ext_vector_type(4))) float f32x4;
typedef __attribute__((address_space(1))) const void* gptr1;
typedef __attribute__((address_space(3))) void* lptr3;

__device__ __forceinline__ unsigned short f2bf(float x) {
    unsigned int u = __builtin_bit_cast(unsigned int, x);
    u += 0x7fffu + ((u >> 16) & 1u);
    return (unsigned short)(u >> 16);
}

// ---------- generic 128x128 B^T GEMM mainloop (bf16 in, fp32 acc) ----------
// A: [rows x K] row-major bf16, Bt: [cols x K] row-major bf16.
// Computes acc[4][4] (16x16 MFMA tiles) for this block's 128x128 output tile.
__device__ __forceinline__ void bt_mainloop(
    const unsigned short* __restrict__ A, const unsigned short* __restrict__ Bt,
    int lda, int ldb, int rowBase, int colBase, int K,
    unsigned short* As, unsigned short* Bs, f32x4 acc[4][4])
{
    const int tid  = threadIdx.x;
    const int lane = tid & 63;
    const int w    = tid >> 6;           // wave 0..3
    const int wr   = (w >> 1) * 64;      // wave row offset in tile
    const int wc   = (w & 1) * 64;       // wave col offset in tile
    const int lr   = lane & 15;
    const int kq   = lane >> 4;          // k-quad

    // staging: LDS tile is [128 rows][32 k] bf16, linear. wave w fills chunks w and w+4
    // (each chunk = 512 elems = 16 rows); lane l -> row chunk*16 + l/4, k (l%4)*8, 16B.
    const int srow0 = w * 16 + (lane >> 2);
    const int skk   = (lane & 3) * 8;

    for (int k0 = 0; k0 < K; k0 += 32) {
#pragma unroll
        for (int j = 0; j < 2; ++j) {
            const unsigned short* ga = A  + (size_t)(rowBase + srow0 + j * 64) * lda + (k0 + skk);
            const unsigned short* gb = Bt + (size_t)(colBase + srow0 + j * 64) * ldb + (k0 + skk);
            __builtin_amdgcn_global_load_lds((gptr1)ga, (lptr3)(As + (j * 4 + w) * 512), 16, 0, 0);
            __builtin_amdgcn_global_load_lds((gptr1)gb, (lptr3)(Bs + (j * 4 + w) * 512), 16, 0, 0);
        }
        asm volatile("s_waitcnt vmcnt(0)" ::: "memory");
        __syncthreads();

        bf16x8 af[4], bq[4];
#pragma unroll
        for (int i = 0; i < 4; ++i) {
            af[i] = *(const bf16x8*)(As + (wr + i * 16 + lr) * 32 + kq * 8);
            bq[i] = *(const bf16x8*)(Bs + (wc + i * 16 + lr) * 32 + kq * 8);
        }
#pragma unroll
        for (int mi = 0; mi < 4; ++mi)
#pragma unroll
            for (int ni = 0; ni < 4; ++ni)
                acc[mi][ni] = __builtin_amdgcn_mfma_f32_16x16x32_bf16(af[mi], bq[ni], acc[mi][ni], 0, 0, 0);
        __syncthreads();
    }
}

#define GEMM_PROLOGUE() \
    __shared__ unsigned short As[128 * 32]; \
    __shared__ unsigned short Bs[128 * 32]; \
    f32x4 acc[4][4]; \
    _Pragma("unroll") for (int i = 0; i < 4; ++i) \
        _Pragma("unroll") for (int j = 0; j < 4; ++j) \
            acc[i][j] = (f32x4){0.f, 0.f, 0.f, 0.f}; \
    const int tid = threadIdx.x; const int lane = tid & 63; const int w = tid >> 6; \
    const int wr = (w >> 1) * 64, wc = (w & 1) * 64, lr = lane & 15, kq = lane >> 4; \
    (void)tid;

// ---------- kernel: prep tn (normalize text[1] rows), copy t1 into out, zero L ----------
__global__ __launch_bounds__(256) void prep_tn_k(
    const float* __restrict__ text, unsigned short* __restrict__ tn,
    float* __restrict__ out, float* __restrict__ L)
{
    const int m = blockIdx.x;
    const int t = threadIdx.x;  // 256
    const float* t1 = text + (size_t)M_SZ * D_SZ;  // row block 1
    float2 v = ((const float2*)(t1 + (size_t)m * D_SZ))[t];
    float s = v.x * v.x + v.y * v.y;
#pragma unroll
    for (int off = 32; off > 0; off >>= 1) s += __shfl_down(s, off);
    __shared__ float partial[4];
    if ((t & 63) == 0) partial[t >> 6] = s;
    __syncthreads();
    float norm = sqrtf(partial[0] + partial[1] + partial[2] + partial[3]);
    norm = fmaxf(norm, 1e-8f);
    const float inv = 1.f / norm;
    ushort2 pk; pk.x = f2bf(v.x * inv); pk.y = f2bf(v.y * inv);
    ((ushort2*)(tn + (size_t)m * D_SZ))[t] = pk;
#pragma unroll
    for (int b = 0; b < B_SZ; ++b)
        ((float2*)(out + ((size_t)(b * M_SZ + m)) * (2 * D_SZ) + D_SZ))[t] = v;
    if (m < 64) L[m * 256 + t] = 0.f;
}

// ---------- kernel: transpose W (fp32 [d][e]) -> Wt (bf16 [e][d]) ----------
__global__ __launch_bounds__(256) void prep_w_k(
    const float* __restrict__ W, unsigned short* __restrict__ Wt)
{
    const int dt = blockIdx.x, et = blockIdx.y;
    const int t = threadIdx.x;
    __shared__ unsigned short tile[64][72];
    const int rr = t >> 4;
    const int cc = (t & 15) * 4;
#pragma unroll
    for (int p = 0; p < 4; ++p) {
        const int d = p * 16 + rr;
        const float4 v = *(const float4*)(W + (size_t)(dt * 64 + d) * D_SZ + et * 64 + cc);
        tile[d][cc] = f2bf(v.x); tile[d][cc + 1] = f2bf(v.y);
        tile[d][cc + 2] = f2bf(v.z); tile[d][cc + 3] = f2bf(v.w);
    }
    __syncthreads();
#pragma unroll
    for (int p = 0; p < 4; ++p) {
        const int e = p * 16 + rr;
        ushort4 pk;
        pk.x = tile[cc][e]; pk.y = tile[cc + 1][e]; pk.z = tile[cc + 2][e]; pk.w = tile[cc + 3][e];
        *(ushort4*)(Wt + (size_t)(et * 64 + e) * D_SZ + dt * 64 + cc) = pk;
    }
}

// ---------- kernel: features fp32 -> V bf16 [b*n][d] and Vt bf16 [b][d][n] ----------
__global__ __launch_bounds__(256) void convert_feat_k(
    const float* __restrict__ feat, unsigned short* __restrict__ V,
    unsigned short* __restrict__ Vt)
{
    const int nt = blockIdx.x, dt = blockIdx.y, b = blockIdx.z;
    const int t = threadIdx.x;
    __shared__ unsigned short tile[64][72];
    const int rr = t >> 4;
    const int cc = (t & 15) * 4;
#pragma unroll
    for (int p = 0; p < 4; ++p) {
        const int r = p * 16 + rr;
        const size_t grow = (size_t)(b * N_SZ + nt * 64 + r);
        const float4 v = *(const float4*)(feat + grow * D_SZ + dt * 64 + cc);
        ushort4 pk; pk.x = f2bf(v.x); pk.y = f2bf(v.y); pk.z = f2bf(v.z); pk.w = f2bf(v.w);
        *(ushort4*)(V + grow * D_SZ + dt * 64 + cc) = pk;
        tile[r][cc] = pk.x; tile[r][cc + 1] = pk.y; tile[r][cc + 2] = pk.z; tile[r][cc + 3] = pk.w;
    }
    __syncthreads();
#pragma unroll
    for (int p = 0; p < 4; ++p) {
        const int d = p * 16 + rr;
        ushort4 pk;
        pk.x = tile[cc][d]; pk.y = tile[cc + 1][d]; pk.z = tile[cc + 2][d]; pk.w = tile[cc + 3][d];
        *(ushort4*)(Vt + ((size_t)(b * D_SZ + dt * 64 + d)) * N_SZ + nt * 64 + cc) = pk;
    }
}

// ---------- kernel: f1 = V @ Wt^T + bias  (fp32 out) ----------
__global__ __launch_bounds__(256) void gemm1_k(
    const unsigned short* __restrict__ V, const unsigned short* __restrict__ Wt,
    const float* __restrict__ bias, float* __restrict__ f1)
{
    GEMM_PROLOGUE();
    const int rowBase = blockIdx.x * 128;
    const int colBase = blockIdx.y * 128;
    bt_mainloop(V, Wt, D_SZ, D_SZ, rowBase, colBase, D_SZ, As, Bs, acc);
#pragma unroll
    for (int mi = 0; mi < 4; ++mi) {
        const int r0 = rowBase + wr + mi * 16 + kq * 4;
#pragma unroll
        for (int ni = 0; ni < 4; ++ni) {
            const int c = colBase + wc + ni * 16 + lr;
            const float bv = bias[c];
#pragma unroll
            for (int r = 0; r < 4; ++r)
                f1[(size_t)(r0 + r) * D_SZ + c] = acc[mi][ni][r] + bv;
        }
    }
}

// ---------- kernel: row-normalize f1 -> fn bf16 ----------
__global__ __launch_bounds__(128) void normalize_k(
    const float* __restrict__ f1, unsigned short* __restrict__ fn)
{
    const int row = blockIdx.x;
    const int t = threadIdx.x;  // 128
    const float4 v = ((const float4*)(f1 + (size_t)row * D_SZ))[t];
    float s = v.x * v.x + v.y * v.y + v.z * v.z + v.w * v.w;
#pragma unroll
    for (int off = 32; off > 0; off >>= 1) s += __shfl_down(s, off);
    __shared__ float partial[2];
    if ((t & 63) == 0) partial[t >> 6] = s;
    __syncthreads();
    float norm = sqrtf(partial[0] + partial[1]);
    norm = fmaxf(norm, 1e-8f);
    const float inv = 1.f / norm;
    ushort4 pk;
    pk.x = f2bf(v.x * inv); pk.y = f2bf(v.y * inv);
    pk.z = f2bf(v.z * inv); pk.w = f2bf(v.w * inv);
    ((ushort4*)(fn + (size_t)row * D_SZ))[t] = pk;
}

// ---------- kernel: sim = fn @ tn^T; E[b][m][n] = bf16(exp(sim)); L[b][m] += sums ----------
__global__ __launch_bounds__(256) void gemm2_k(
    const unsigned short* __restrict__ fn, const unsigned short* __restrict__ tn,
    unsigned short* __restrict__ E, float* __restrict__ L)
{
    GEMM_PROLOGUE();
    const int rowBase = blockIdx.x * 128;   // global row = b*N + n
    const int colBase = blockIdx.y * 128;   // m
    bt_mainloop(fn, tn, D_SZ, D_SZ, rowBase, colBase, D_SZ, As, Bs, acc);

    const int b  = rowBase >> 12;       // rowBase / 4096 (blocks never straddle batches)
    const int nb = rowBase & 4095;
    unsigned short* Eb = E + (size_t)b * M_SZ * N_SZ;
#pragma unroll
    for (int ni = 0; ni < 4; ++ni) {
        const int m = colBase + wc + ni * 16 + lr;
        float p = 0.f;
#pragma unroll
        for (int mi = 0; mi < 4; ++mi) {
            const int n0 = nb + wr + mi * 16 + kq * 4;
            const float e0 = __expf(acc[mi][ni][0]);
            const float e1 = __expf(acc[mi][ni][1]);
            const float e2 = __expf(acc[mi][ni][2]);
            const float e3 = __expf(acc[mi][ni][3]);
            ushort4 pk; pk.x = f2bf(e0); pk.y = f2bf(e1); pk.z = f2bf(e2); pk.w = f2bf(e3);
            *(ushort4*)(Eb + (size_t)m * N_SZ + n0) = pk;
            p += (e0 + e1) + (e2 + e3);
        }
        // reduce the 4 k-quads holding the same m column (lanes l, l+16, l+32, l+48)
        p += __shfl_down(p, 16);
        p += __shfl_down(p, 32);
        if (lane < 16) atomicAdd(&L[b * M_SZ + m], p);
    }
}

// ---------- kernel: fm = (E @ Vt^T) / L; write into out left half ----------
__global__ __launch_bounds__(256) void gemm3_k(
    const unsigned short* __restrict__ E, const unsigned short* __restrict__ Vt,
    const float* __restrict__ L, float* __restrict__ out)
{
    GEMM_PROLOGUE();
    const int b = blockIdx.z;
    const int rowBase = blockIdx.x * 128;   // m
    const int colBase = blockIdx.y * 128;   // d
    const unsigned short* Ab = E + (size_t)b * M_SZ * N_SZ;
    const unsigned short* Bb = Vt + (size_t)b * D_SZ * N_SZ;
    bt_mainloop(Ab, Bb, N_SZ, N_SZ, rowBase, colBase, N_SZ, As, Bs, acc);

#pragma unroll
    for (int mi = 0; mi < 4; ++mi) {
        const int r0 = rowBase + wr + mi * 16 + kq * 4;
        float invl[4];
#pragma unroll
        for (int r = 0; r < 4; ++r) invl[r] = 1.f / L[b * M_SZ + r0 + r];
#pragma unroll
        for (int ni = 0; ni < 4; ++ni) {
            const int d = colBase + wc + ni * 16 + lr;
#pragma unroll
            for (int r = 0; r < 4; ++r)
                out[((size_t)(b * M_SZ + r0 + r)) * (2 * D_SZ) + d] = acc[mi][ni][r] * invl[r];
        }
    }
}

extern "C" void kernel_launch(void* const* d_in, const int* in_sizes, int n_in,
                              void* d_out, int out_size, void* d_ws, size_t ws_size,
                              hipStream_t stream) {
    const float* features = (const float*)d_in[0];   // [8, 4096, 512]
    const float* text     = (const float*)d_in[1];   // [2, 2048, 512]
    const float* W        = (const float*)d_in[2];   // [512, 512]
    const float* bias     = (const float*)d_in[3];   // [512]
    float* out = (float*)d_out;                      // [8, 2048, 1024]
    char* ws = (char*)d_ws;

    // workspace layout (bytes)
    unsigned short* fn = (unsigned short*)(ws + 0);            // 32 MiB  [32768][512] bf16
    unsigned short* tn = (unsigned short*)(ws + 33554432);     //  2 MiB  [2048][512] bf16
    unsigned short* Wt = (unsigned short*)(ws + 35651584);     // .5 MiB  [512][512] bf16
    unsigned short* V  = (unsigned short*)(ws + 36175872);     // 32 MiB  [32768][512] bf16
    unsigned short* Vt = (unsigned short*)(ws + 69730304);     // 32 MiB  [8][512][4096] bf16
    float*          L  = (float*)(ws + 103284736);             // 64 KiB  [8][2048] f32
    float*          f1 = (float*)(ws + 103350272);             // 64 MiB  [32768][512] f32 (aliases E)
    unsigned short* E  = (unsigned short*)(ws + 103350272);    // 128 MiB [8][2048][4096] bf16

    hipLaunchKernelGGL(prep_tn_k, dim3(M_SZ), dim3(256), 0, stream, text, tn, out, L);
    hipLaunchKernelGGL(prep_w_k, dim3(8, 8), dim3(256), 0, stream, W, Wt);
    hipLaunchKernelGGL(convert_feat_k, dim3(64, 8, 8), dim3(256), 0, stream, features, V, Vt);
    hipLaunchKernelGGL(gemm1_k, dim3(256, 4), dim3(256), 0, stream, V, Wt, bias, f1);
    hipLaunchKernelGGL(normalize_k, dim3(32768), dim3(128), 0, stream, f1, fn);
    hipLaunchKernelGGL(gemm2_k, dim3(256, 16), dim3(256), 0, stream, fn, tn, E, L);
    hipLaunchKernelGGL(gemm3_k, dim3(16, 4, 8), dim3(256), 0, stream, E, Vt, L, out);
}

// Round 2
// 383.453 us; speedup vs baseline: 1.0655x; 1.0655x over previous
//
#include <hip/hip_runtime.h>

#define B_SZ 8
#define N_SZ 4096
#define M_SZ 2048
#define D_SZ 512

typedef __attribute__((ext_vector_type(8))) short bf16x8;
typedef __attribute__((ext_vector_type(4))) float f32x4;
typedef __attribute__((address_space(1))) const void* gptr1;
typedef __attribute__((address_space(3))) void* lptr3;

__device__ __forceinline__ unsigned short f2bf(float x) {
    unsigned int u = __builtin_bit_cast(unsigned int, x);
    u += 0x7fffu + ((u >> 16) & 1u);
    return (unsigned short)(u >> 16);
}
__device__ __forceinline__ float bf2f(unsigned short u) {
    unsigned int x = ((unsigned int)u) << 16;
    return __builtin_bit_cast(float, x);
}

// ---------- generic 128x128 B^T GEMM mainloop (bf16 in, fp32 acc) ----------
__device__ __forceinline__ void bt_mainloop(
    const unsigned short* __restrict__ A, const unsigned short* __restrict__ Bt,
    int lda, int ldb, int rowBase, int colBase, int K,
    unsigned short* As, unsigned short* Bs, f32x4 acc[4][4])
{
    const int tid  = threadIdx.x;
    const int lane = tid & 63;
    const int w    = tid >> 6;
    const int wr   = (w >> 1) * 64;
    const int wc   = (w & 1) * 64;
    const int lr   = lane & 15;
    const int kq   = lane >> 4;

    const int srow0 = w * 16 + (lane >> 2);
    const int skk   = (lane & 3) * 8;

    for (int k0 = 0; k0 < K; k0 += 32) {
#pragma unroll
        for (int j = 0; j < 2; ++j) {
            const unsigned short* ga = A  + (size_t)(rowBase + srow0 + j * 64) * lda + (k0 + skk);
            const unsigned short* gb = Bt + (size_t)(colBase + srow0 + j * 64) * ldb + (k0 + skk);
            __builtin_amdgcn_global_load_lds((gptr1)ga, (lptr3)(As + (j * 4 + w) * 512), 16, 0, 0);
            __builtin_amdgcn_global_load_lds((gptr1)gb, (lptr3)(Bs + (j * 4 + w) * 512), 16, 0, 0);
        }
        asm volatile("s_waitcnt vmcnt(0)" ::: "memory");
        __syncthreads();

        bf16x8 af[4], bq[4];
#pragma unroll
        for (int i = 0; i < 4; ++i) {
            af[i] = *(const bf16x8*)(As + (wr + i * 16 + lr) * 32 + kq * 8);
            bq[i] = *(const bf16x8*)(Bs + (wc + i * 16 + lr) * 32 + kq * 8);
        }
#pragma unroll
        for (int mi = 0; mi < 4; ++mi)
#pragma unroll
            for (int ni = 0; ni < 4; ++ni)
                acc[mi][ni] = __builtin_amdgcn_mfma_f32_16x16x32_bf16(af[mi], bq[ni], acc[mi][ni], 0, 0, 0);
        __syncthreads();
    }
}

// ---------- prep: normalize text[1] rows -> tn, copy t1 into out, zero L & SS ----------
__global__ __launch_bounds__(256) void prep_tn_k(
    const float* __restrict__ text, unsigned short* __restrict__ tn,
    float* __restrict__ out, float* __restrict__ L, float* __restrict__ SS)
{
    const int m = blockIdx.x;
    const int t = threadIdx.x;  // 256
    const float* t1 = text + (size_t)M_SZ * D_SZ;
    float2 v = ((const float2*)(t1 + (size_t)m * D_SZ))[t];
    float s = v.x * v.x + v.y * v.y;
#pragma unroll
    for (int off = 32; off > 0; off >>= 1) s += __shfl_down(s, off);
    __shared__ float partial[4];
    if ((t & 63) == 0) partial[t >> 6] = s;
    __syncthreads();
    float norm = sqrtf(partial[0] + partial[1] + partial[2] + partial[3]);
    norm = fmaxf(norm, 1e-8f);
    const float inv = 1.f / norm;
    ushort2 pk; pk.x = f2bf(v.x * inv); pk.y = f2bf(v.y * inv);
    ((ushort2*)(tn + (size_t)m * D_SZ))[t] = pk;
#pragma unroll
    for (int b = 0; b < B_SZ; ++b)
        ((float2*)(out + ((size_t)(b * M_SZ + m)) * (2 * D_SZ) + D_SZ))[t] = v;
    if (m < 64) L[m * 256 + t] = 0.f;
    if (m < 128) SS[m * 256 + t] = 0.f;
}

// ---------- prep: transpose W (fp32 [d][e]) -> Wt (bf16 [e][d]) ----------
__global__ __launch_bounds__(256) void prep_w_k(
    const float* __restrict__ W, unsigned short* __restrict__ Wt)
{
    const int dt = blockIdx.x, et = blockIdx.y;
    const int t = threadIdx.x;
    __shared__ unsigned short tile[64][72];
    const int rr = t >> 4;
    const int cc = (t & 15) * 4;
#pragma unroll
    for (int p = 0; p < 4; ++p) {
        const int d = p * 16 + rr;
        const float4 v = *(const float4*)(W + (size_t)(dt * 64 + d) * D_SZ + et * 64 + cc);
        tile[d][cc] = f2bf(v.x); tile[d][cc + 1] = f2bf(v.y);
        tile[d][cc + 2] = f2bf(v.z); tile[d][cc + 3] = f2bf(v.w);
    }
    __syncthreads();
#pragma unroll
    for (int p = 0; p < 4; ++p) {
        const int e = p * 16 + rr;
        ushort4 pk;
        pk.x = tile[cc][e]; pk.y = tile[cc + 1][e]; pk.z = tile[cc + 2][e]; pk.w = tile[cc + 3][e];
        *(ushort4*)(Wt + (size_t)(et * 64 + e) * D_SZ + dt * 64 + cc) = pk;
    }
}

// ---------- features fp32 -> V bf16 [b*n][d] and Vt bf16 [b][d][n] ----------
__global__ __launch_bounds__(256) void convert_feat_k(
    const float* __restrict__ feat, unsigned short* __restrict__ V,
    unsigned short* __restrict__ Vt)
{
    const int nt = blockIdx.x, dt = blockIdx.y, b = blockIdx.z;
    const int t = threadIdx.x;
    __shared__ unsigned short tile[64][72];
    const int rr = t >> 4;
    const int cc = (t & 15) * 4;
#pragma unroll
    for (int p = 0; p < 4; ++p) {
        const int r = p * 16 + rr;
        const size_t grow = (size_t)(b * N_SZ + nt * 64 + r);
        const float4 v = *(const float4*)(feat + grow * D_SZ + dt * 64 + cc);
        ushort4 pk; pk.x = f2bf(v.x); pk.y = f2bf(v.y); pk.z = f2bf(v.z); pk.w = f2bf(v.w);
        *(ushort4*)(V + grow * D_SZ + dt * 64 + cc) = pk;
        tile[r][cc] = pk.x; tile[r][cc + 1] = pk.y; tile[r][cc + 2] = pk.z; tile[r][cc + 3] = pk.w;
    }
    __syncthreads();
#pragma unroll
    for (int p = 0; p < 4; ++p) {
        const int d = p * 16 + rr;
        ushort4 pk;
        pk.x = tile[cc][d]; pk.y = tile[cc + 1][d]; pk.z = tile[cc + 2][d]; pk.w = tile[cc + 3][d];
        *(ushort4*)(Vt + ((size_t)(b * D_SZ + dt * 64 + d)) * N_SZ + nt * 64 + cc) = pk;
    }
}

// ---------- gemm1: f1b = bf16(V @ Wt^T + bias); SS[row] += sum(f1^2) (fp32, pre-round) ----------
__global__ __launch_bounds__(256) void gemm1_k(
    const unsigned short* __restrict__ V, const unsigned short* __restrict__ Wt,
    const float* __restrict__ bias, unsigned short* __restrict__ f1b,
    float* __restrict__ SS)
{
    __shared__ unsigned short As[128 * 32];
    __shared__ unsigned short Bs[128 * 32];
    f32x4 acc[4][4];
#pragma unroll
    for (int i = 0; i < 4; ++i)
#pragma unroll
        for (int j = 0; j < 4; ++j) acc[i][j] = (f32x4){0.f, 0.f, 0.f, 0.f};
    const int tid = threadIdx.x, lane = tid & 63, w = tid >> 6;
    const int wr = (w >> 1) * 64, wc = (w & 1) * 64, lr = lane & 15, kq = lane >> 4;

    const int rowBase = blockIdx.x * 128;
    const int colBase = blockIdx.y * 128;
    bt_mainloop(V, Wt, D_SZ, D_SZ, rowBase, colBase, D_SZ, As, Bs, acc);

#pragma unroll
    for (int mi = 0; mi < 4; ++mi) {
        const int r0 = rowBase + wr + mi * 16 + kq * 4;
        float s[4] = {0.f, 0.f, 0.f, 0.f};
#pragma unroll
        for (int ni = 0; ni < 4; ++ni) {
            const int c = colBase + wc + ni * 16 + lr;
            const float bv = bias[c];
#pragma unroll
            for (int r = 0; r < 4; ++r) {
                const float v = acc[mi][ni][r] + bv;
                f1b[(size_t)(r0 + r) * D_SZ + c] = f2bf(v);
                s[r] += v * v;
            }
        }
        // reduce sum-sq across the 16 lr lanes (cols); kq groups hold distinct rows
#pragma unroll
        for (int off = 1; off <= 8; off <<= 1)
#pragma unroll
            for (int r = 0; r < 4; ++r) s[r] += __shfl_xor(s[r], off);
        if (lr == 0) {
#pragma unroll
            for (int r = 0; r < 4; ++r) atomicAdd(&SS[r0 + r], s[r]);
        }
    }
}

// ---------- normalize: fn = bf16(f1b * rsqrt-ish(SS)) ----------
__global__ __launch_bounds__(128) void normalize_k(
    const unsigned short* __restrict__ f1b, const float* __restrict__ SS,
    unsigned short* __restrict__ fn)
{
    const int row = blockIdx.x;
    const int t = threadIdx.x;  // 128
    const float norm = fmaxf(sqrtf(SS[row]), 1e-8f);
    const float inv = 1.f / norm;
    ushort4 v = ((const ushort4*)(f1b + (size_t)row * D_SZ))[t];
    ushort4 o;
    o.x = f2bf(bf2f(v.x) * inv); o.y = f2bf(bf2f(v.y) * inv);
    o.z = f2bf(bf2f(v.z) * inv); o.w = f2bf(bf2f(v.w) * inv);
    ((ushort4*)(fn + (size_t)row * D_SZ))[t] = o;
}

// ---------- gemm2: sim = fn @ tn^T; E[b][m][n] = bf16(exp(sim)); L[b][m] += sums ----------
// 1D grid, XCD-aware swizzle: each XCD walks all 16 m-tiles of one fn row-tile
// consecutively (fn row-tile stays L2-resident; all of tn (2 MiB) L2-resident).
__global__ __launch_bounds__(256) void gemm2_k(
    const unsigned short* __restrict__ fn, const unsigned short* __restrict__ tn,
    unsigned short* __restrict__ E, float* __restrict__ L)
{
    __shared__ unsigned short smem[128 * 136];  // 34816 B: staging (8 KB x2) then P-tile
    unsigned short* As = smem;
    unsigned short* Bs = smem + 4096;
    f32x4 acc[4][4];
#pragma unroll
    for (int i = 0; i < 4; ++i)
#pragma unroll
        for (int j = 0; j < 4; ++j) acc[i][j] = (f32x4){0.f, 0.f, 0.f, 0.f};
    const int tid = threadIdx.x, lane = tid & 63, w = tid >> 6;
    const int wr = (w >> 1) * 64, wc = (w & 1) * 64, lr = lane & 15, kq = lane >> 4;

    const int lin = blockIdx.x;
    const int xcd = lin & 7, slot = lin >> 3;
    const int mt = slot & 15;                 // m-tile (inner)
    const int rt = (slot >> 4) * 8 + xcd;     // fn row-tile
    const int rowBase = rt * 128;
    const int colBase = mt * 128;

    bt_mainloop(fn, tn, D_SZ, D_SZ, rowBase, colBase, D_SZ, As, Bs, acc);

    const int b  = rowBase >> 12;
    const int nb = rowBase & 4095;
    unsigned short* Eb = E + (size_t)b * M_SZ * N_SZ;
    unsigned short* P = smem;                 // [mm][nn], stride 136 (reuses staging LDS)

#pragma unroll
    for (int ni = 0; ni < 4; ++ni) {
        const int mm = wc + ni * 16 + lr;
        float p = 0.f;
#pragma unroll
        for (int mi = 0; mi < 4; ++mi) {
            const int nn0 = wr + mi * 16 + kq * 4;
            const float e0 = __expf(acc[mi][ni][0]);
            const float e1 = __expf(acc[mi][ni][1]);
            const float e2 = __expf(acc[mi][ni][2]);
            const float e3 = __expf(acc[mi][ni][3]);
            ushort4 pk; pk.x = f2bf(e0); pk.y = f2bf(e1); pk.z = f2bf(e2); pk.w = f2bf(e3);
            *(ushort4*)(P + mm * 136 + nn0) = pk;
            p += (e0 + e1) + (e2 + e3);
        }
        p += __shfl_down(p, 16);
        p += __shfl_down(p, 32);
        if (lane < 16) atomicAdd(&L[b * M_SZ + colBase + mm], p);
    }
    __syncthreads();

    // coalesced E store: 16 lanes cover 128 contiguous n-bytes... 16B/lane along n
    const int tr = tid >> 4;
    const int tc = (tid & 15) * 8;
#pragma unroll
    for (int j = 0; j < 8; ++j) {
        const int mm = j * 16 + tr;
        bf16x8 v = *(const bf16x8*)(P + mm * 136 + tc);
        *(bf16x8*)(Eb + (size_t)(colBase + mm) * N_SZ + nb + tc) = v;
    }
}

// ---------- gemm3: fm = (E @ Vt^T) / L -> out left half ----------
__global__ __launch_bounds__(256) void gemm3_k(
    const unsigned short* __restrict__ E, const unsigned short* __restrict__ Vt,
    const float* __restrict__ L, float* __restrict__ out)
{
    __shared__ unsigned short As[128 * 32];
    __shared__ unsigned short Bs[128 * 32];
    f32x4 acc[4][4];
#pragma unroll
    for (int i = 0; i < 4; ++i)
#pragma unroll
        for (int j = 0; j < 4; ++j) acc[i][j] = (f32x4){0.f, 0.f, 0.f, 0.f};
    const int tid = threadIdx.x, lane = tid & 63, w = tid >> 6;
    const int wr = (w >> 1) * 64, wc = (w & 1) * 64, lr = lane & 15, kq = lane >> 4;

    const int b = blockIdx.z;
    const int rowBase = blockIdx.x * 128;   // m
    const int colBase = blockIdx.y * 128;   // d
    const unsigned short* Ab = E + (size_t)b * M_SZ * N_SZ;
    const unsigned short* Bb = Vt + (size_t)b * D_SZ * N_SZ;
    bt_mainloop(Ab, Bb, N_SZ, N_SZ, rowBase, colBase, N_SZ, As, Bs, acc);

#pragma unroll
    for (int mi = 0; mi < 4; ++mi) {
        const int r0 = rowBase + wr + mi * 16 + kq * 4;
        float invl[4];
#pragma unroll
        for (int r = 0; r < 4; ++r) invl[r] = 1.f / L[b * M_SZ + r0 + r];
#pragma unroll
        for (int ni = 0; ni < 4; ++ni) {
            const int d = colBase + wc + ni * 16 + lr;
#pragma unroll
            for (int r = 0; r < 4; ++r)
                out[((size_t)(b * M_SZ + r0 + r)) * (2 * D_SZ) + d] = acc[mi][ni][r] * invl[r];
        }
    }
}

extern "C" void kernel_launch(void* const* d_in, const int* in_sizes, int n_in,
                              void* d_out, int out_size, void* d_ws, size_t ws_size,
                              hipStream_t stream) {
    const float* features = (const float*)d_in[0];   // [8, 4096, 512]
    const float* text     = (const float*)d_in[1];   // [2, 2048, 512]
    const float* W        = (const float*)d_in[2];   // [512, 512]
    const float* bias     = (const float*)d_in[3];   // [512]
    float* out = (float*)d_out;                      // [8, 2048, 1024]
    char* ws = (char*)d_ws;

    // workspace layout (bytes)
    unsigned short* fn  = (unsigned short*)(ws + 0);            // 32 MiB
    unsigned short* tn  = (unsigned short*)(ws + 33554432);     //  2 MiB
    unsigned short* Wt  = (unsigned short*)(ws + 35651584);     // .5 MiB
    unsigned short* V   = (unsigned short*)(ws + 36175872);     // 32 MiB
    unsigned short* Vt  = (unsigned short*)(ws + 69730304);     // 32 MiB
    float*          L   = (float*)(ws + 103284736);             // 64 KiB
    float*          SS  = (float*)(ws + 103350272);             // 128 KiB
    unsigned short* E   = (unsigned short*)(ws + 103481344);    // 128 MiB
    unsigned short* f1b = (unsigned short*)(ws + 103481344);    // 32 MiB (aliases E; dead before gemm2)

    hipLaunchKernelGGL(prep_tn_k, dim3(M_SZ), dim3(256), 0, stream, text, tn, out, L, SS);
    hipLaunchKernelGGL(prep_w_k, dim3(8, 8), dim3(256), 0, stream, W, Wt);
    hipLaunchKernelGGL(convert_feat_k, dim3(64, 8, 8), dim3(256), 0, stream, features, V, Vt);
    hipLaunchKernelGGL(gemm1_k, dim3(256, 4), dim3(256), 0, stream, V, Wt, bias, f1b, SS);
    hipLaunchKernelGGL(normalize_k, dim3(32768), dim3(128), 0, stream, f1b, SS, fn);
    hipLaunchKernelGGL(gemm2_k, dim3(4096), dim3(256), 0, stream, fn, tn, E, L);
    hipLaunchKernelGGL(gemm3_k, dim3(16, 4, 8), dim3(256), 0, stream, E, Vt, L, out);
}